// Round 1
// baseline (2141.838 us; speedup 1.0000x reference)
//
#include <hip/hip_runtime.h>
#include <math.h>

#define N_NODES 100000
#define N_EDGES 1600000
#define FEATP 132      // 131 padded to 132 (col 131 = 0)
#define KPAD0 192      // K for layer-0 GEMM padded to multiple of 64 (W0p rows 131..191 = 0)
#define HID 128

__device__ __forceinline__ float geluf(float x) {
    return 0.5f * x * (1.0f + erff(x * 0.7071067811865475f));
}
__device__ __forceinline__ float leakyf(float x) {
    return x >= 0.0f ? x : 0.2f * x;
}
__device__ __forceinline__ float wave_reduce_max(float v) {
#pragma unroll
    for (int o = 32; o > 0; o >>= 1) v = fmaxf(v, __shfl_xor(v, o, 64));
    return v;
}
__device__ __forceinline__ float wave_reduce_sum(float v) {
#pragma unroll
    for (int o = 32; o > 0; o >>= 1) v += __shfl_xor(v, o, 64);
    return v;
}

// ---------------- GEMM: C[M x N] = act(A[M x K] @ B[K x N] + bias) ----------------
// LDS-free "scalar-A, B-in-registers" design.
// One wave = 16 rows x 64 cols. lane = output column (blockIdx.y*64 + lane).
// Per 64-deep K chunk: wave stages B[k][col] in 64 VGPRs (coalesced, L2-hot),
// then per row reads A[row][k0..k0+63] at a wave-uniform address (scalar loads
// through the constant cache) and issues v_fmac acc, s, v.
// Requires: K a multiple of 64; B has K rows (zero-padded); A buffer readable
// for (M-1)*lda + K elements (caller pads the workspace node buffer tail).
// ACT: 0=none, 1=gelu.
template <int ACT>
__global__ __launch_bounds__(256, 3) void gemm_rw(
    const float* __restrict__ A, int lda, int M, int K,
    const float* __restrict__ B, int ldb,
    const float* __restrict__ bias,
    float* __restrict__ C, int ldc, int colOff,
    const int* __restrict__ rowIdx)
{
    const int lane = threadIdx.x & 63;
    const int wid  = __builtin_amdgcn_readfirstlane(threadIdx.x >> 6);
    const int rbase = (blockIdx.x * 4 + wid) * 16;
    if (rbase >= M) return;
    const int ncol = blockIdx.y * 64 + lane;

    float acc[16];
#pragma unroll
    for (int r = 0; r < 16; ++r) acc[r] = 0.0f;

    const int T = K >> 6;
    for (int t = 0; t < T; ++t) {
        const float* __restrict__ bp = B + (size_t)(t << 6) * ldb + ncol;
        float breg[64];
#pragma unroll
        for (int kk = 0; kk < 64; ++kk) breg[kk] = bp[(size_t)kk * ldb];
#pragma unroll
        for (int r = 0; r < 16; ++r) {
            int row = rbase + r;
            row = row < M ? row : M - 1;          // uniform clamp (tail waves)
            const float* __restrict__ ap = A + (size_t)row * lda + (t << 6);
            float p0 = 0.f, p1 = 0.f, p2 = 0.f, p3 = 0.f;
#pragma unroll
            for (int kk = 0; kk < 64; kk += 4) {  // 4 indep chains hide FMA latency
                p0 = fmaf(ap[kk + 0], breg[kk + 0], p0);
                p1 = fmaf(ap[kk + 1], breg[kk + 1], p1);
                p2 = fmaf(ap[kk + 2], breg[kk + 2], p2);
                p3 = fmaf(ap[kk + 3], breg[kk + 3], p3);
            }
            acc[r] += (p0 + p1) + (p2 + p3);
        }
    }

    const float bv = bias ? bias[blockIdx.y * 64 + lane] : 0.0f;
#pragma unroll
    for (int r = 0; r < 16; ++r) {
        int row = rbase + r;
        if (row >= M) break;
        int orow = rowIdx ? rowIdx[row] : row;
        float x = acc[r] + bv;
        if (ACT == 1) x = geluf(x);
        C[(size_t)orow * ldc + colOff + blockIdx.y * 64 + lane] = x;
    }
}

// node[ci[n]][128+j] = gelu(ars[n][j]) for j<3; node[ci[n]][131] = 0
__global__ void ars_kernel(const float* __restrict__ ars, const int* __restrict__ ci,
                           float* __restrict__ node)
{
    int i = blockIdx.x * blockDim.x + threadIdx.x;
    if (i >= N_NODES * 4) return;
    int n = i >> 2, j = i & 3;
    float v = (j < 3) ? geluf(ars[n * 3 + j]) : 0.0f;
    node[(size_t)ci[n] * FEATP + 128 + j] = v;
}

// W0p[192 x 128]: rows 0..130 copy of W0, rows 131..191 zero
__global__ void pad_W0(const float* __restrict__ W0, float* __restrict__ W0p)
{
    int i = blockIdx.x * blockDim.x + threadIdx.x;
    if (i >= KPAD0 * HID) return;
    int r = i >> 7;
    W0p[i] = (r < 131) ? W0[i] : 0.0f;
}

// ---------------- CSR build (by dst) ----------------
__global__ void hist_dst(const int* __restrict__ edges, int* __restrict__ deg)
{
    int e = blockIdx.x * blockDim.x + threadIdx.x;
    if (e < N_EDGES) atomicAdd(&deg[edges[2 * e + 1]], 1);
}

// block-local exclusive scan: out[i] = excl-prefix within block; partials[b] = block sum
__global__ __launch_bounds__(1024) void scan_local(const int* __restrict__ deg,
                                                   int* __restrict__ out,
                                                   int* __restrict__ partials)
{
    __shared__ int sw[16];
    int tid = threadIdx.x;
    int gid = blockIdx.x * 1024 + tid;
    int lane = tid & 63, w = tid >> 6;
    int v = (gid < N_NODES) ? deg[gid] : 0;
    int x = v;
#pragma unroll
    for (int off = 1; off < 64; off <<= 1) {
        int t = __shfl_up(x, off, 64);
        if (lane >= off) x += t;
    }
    if (lane == 63) sw[w] = x;
    __syncthreads();
    if (tid < 64) {
        int y = (tid < 16) ? sw[tid] : 0;
#pragma unroll
        for (int off = 1; off < 16; off <<= 1) {
            int t = __shfl_up(y, off, 64);
            if (tid >= off) y += t;
        }
        if (tid < 16) sw[tid] = y;
    }
    __syncthreads();
    int base = (w > 0) ? sw[w - 1] : 0;
    if (gid < N_NODES) out[gid] = base + x - v;
    if (tid == 1023) partials[blockIdx.x] = base + x;
}

// add cross-block offsets; set row_ptr[N] = E (total degree is E by construction)
__global__ __launch_bounds__(1024) void scan_add(int* __restrict__ row_ptr,
                                                 const int* __restrict__ partials)
{
    __shared__ int soff;
    int b = blockIdx.x, tid = threadIdx.x;
    if (tid < 64) {
        int acc = 0;
        for (int i = tid; i < b; i += 64) acc += partials[i];
        acc = (int)wave_reduce_sum((float)0) + acc;  // keep types simple below
        // integer wave reduction:
#pragma unroll
        for (int o = 32; o > 0; o >>= 1) acc += __shfl_xor(acc, o, 64);
        if (tid == 0) soff = acc;
    }
    __syncthreads();
    int gid = b * 1024 + tid;
    if (gid < N_NODES) row_ptr[gid] += soff;
    if (b == 0 && tid == 0) row_ptr[N_NODES] = N_EDGES;
}

__global__ void copy_int(const int* __restrict__ src, int* __restrict__ dst, int n)
{
    int i = blockIdx.x * blockDim.x + threadIdx.x;
    if (i < n) dst[i] = src[i];
}

__global__ void scatter_csr(const int* __restrict__ edges, int* __restrict__ cursor,
                            int* __restrict__ csr_src)
{
    int e = blockIdx.x * blockDim.x + threadIdx.x;
    if (e >= N_EDGES) return;
    int s = edges[2 * e], d = edges[2 * e + 1];
    int pos = atomicAdd(&cursor[d], 1);
    csr_src[pos] = s;
}

// ---------------- attention scalars ----------------
__global__ __launch_bounds__(256) void attn_scores(
    const float* __restrict__ h, const float* __restrict__ atts,
    const float* __restrict__ attd, float* __restrict__ as_, float* __restrict__ ad_)
{
    int lane = threadIdx.x & 63;
    int node = blockIdx.x * 4 + (threadIdx.x >> 6);
    if (node >= N_NODES) return;
    float h0 = h[(size_t)node * HID + lane];
    float h1 = h[(size_t)node * HID + 64 + lane];
    float s = h0 * atts[lane] + h1 * atts[64 + lane];
    float d = h0 * attd[lane] + h1 * attd[64 + lane];
    s = wave_reduce_sum(s);
    d = wave_reduce_sum(d);
    if (lane == 0) { as_[node] = s; ad_[node] = d; }
}

// ---------------- GAT softmax-aggregate, one wave per dst node ----------------
template <int ACT>
__global__ __launch_bounds__(256) void gat_aggregate(
    const float* __restrict__ h,
    const float* __restrict__ as_, const float* __restrict__ ad_,
    const int* __restrict__ row_ptr, const int* __restrict__ csr_src,
    const float* __restrict__ bias, float* __restrict__ outp)
{
    int lane = threadIdx.x & 63;
    int node = blockIdx.x * 4 + (threadIdx.x >> 6);
    if (node >= N_NODES) return;
    int start = row_ptr[node];
    int deg = row_ptr[node + 1] - start;
    float adn = ad_[node];
    float e_self = leakyf(as_[node] + adn);
    float acc0 = 0.0f, acc1 = 0.0f;
    float m, denom;

    if (deg <= 64) {
        int s = 0;
        float e = -INFINITY;
        if (lane < deg) {
            s = csr_src[start + lane];
            e = leakyf(as_[s] + adn);
        }
        m = fmaxf(wave_reduce_max(e), e_self);
        float w = (lane < deg) ? __expf(e - m) : 0.0f;
        denom = wave_reduce_sum(w) + __expf(e_self - m);
        for (int jj = 0; jj < deg; ++jj) {
            int sj = __shfl(s, jj, 64);
            float wj = __shfl(w, jj, 64);
            acc0 += wj * h[(size_t)sj * HID + lane];
            acc1 += wj * h[(size_t)sj * HID + 64 + lane];
        }
    } else {
        float lm = -INFINITY;
        for (int j = lane; j < deg; j += 64)
            lm = fmaxf(lm, leakyf(as_[csr_src[start + j]] + adn));
        m = fmaxf(wave_reduce_max(lm), e_self);
        float lsum = 0.0f;
        for (int j = lane; j < deg; j += 64)
            lsum += __expf(leakyf(as_[csr_src[start + j]] + adn) - m);
        denom = wave_reduce_sum(lsum) + __expf(e_self - m);
        for (int c0 = 0; c0 < deg; c0 += 64) {
            int j = c0 + lane;
            int s = 0;
            float w = 0.0f;
            if (j < deg) {
                s = csr_src[start + j];
                w = __expf(leakyf(as_[s] + adn) - m);
            }
            int cnt = min(64, deg - c0);
            for (int jj = 0; jj < cnt; ++jj) {
                int sj = __shfl(s, jj, 64);
                float wj = __shfl(w, jj, 64);
                acc0 += wj * h[(size_t)sj * HID + lane];
                acc1 += wj * h[(size_t)sj * HID + 64 + lane];
            }
        }
    }

    float wself = __expf(e_self - m);
    acc0 = (acc0 + wself * h[(size_t)node * HID + lane]) / denom;
    acc1 = (acc1 + wself * h[(size_t)node * HID + 64 + lane]) / denom;
    acc0 += bias[lane];
    acc1 += bias[64 + lane];
    if (ACT == 0) {
        acc0 = fmaxf(acc0, 0.0f);
        acc1 = fmaxf(acc1, 0.0f);
    } else {
        acc0 = geluf(acc0);
        acc1 = geluf(acc1);
    }
    outp[(size_t)node * HID + lane] = acc0;
    outp[(size_t)node * HID + 64 + lane] = acc1;
}

// ---------------- heads: pack [a0,a1,d0,d1] per node ----------------
__global__ __launch_bounds__(256) void head_proj(
    const float* __restrict__ outf,
    const float* __restrict__ Wa, const float* __restrict__ ba,
    const float* __restrict__ Wd, const float* __restrict__ bd,
    float* __restrict__ adp)
{
    int lane = threadIdx.x & 63;
    int node = blockIdx.x * 4 + (threadIdx.x >> 6);
    if (node >= N_NODES) return;
    float o0 = outf[(size_t)node * HID + lane];
    float o1 = outf[(size_t)node * HID + 64 + lane];
    float a0 = o0 * Wa[lane * 2] + o1 * Wa[(lane + 64) * 2];
    float a1 = o0 * Wa[lane * 2 + 1] + o1 * Wa[(lane + 64) * 2 + 1];
    float d0 = o0 * Wd[lane * 2] + o1 * Wd[(lane + 64) * 2];
    float d1 = o0 * Wd[lane * 2 + 1] + o1 * Wd[(lane + 64) * 2 + 1];
    a0 = wave_reduce_sum(a0);
    a1 = wave_reduce_sum(a1);
    d0 = wave_reduce_sum(d0);
    d1 = wave_reduce_sum(d1);
    if (lane == 0) {
        float4 v = make_float4(a0 + ba[0], a1 + ba[1], d0 + bd[0], d1 + bd[1]);
        ((float4*)adp)[node] = v;
    }
}

__global__ void edge_pred(const int* __restrict__ edges, const float* __restrict__ adp,
                          float* __restrict__ pred)
{
    int e = blockIdx.x * blockDim.x + threadIdx.x;
    if (e >= N_EDGES) return;
    int s = edges[2 * e], d = edges[2 * e + 1];
    float4 ps = ((const float4*)adp)[s];
    float4 pd = ((const float4*)adp)[d];
    pred[2 * e] = ps.x * pd.x + ps.y * pd.y;
    pred[2 * e + 1] = ps.z * pd.z + ps.w * pd.w;
}

extern "C" void kernel_launch(void* const* d_in, const int* in_sizes, int n_in,
                              void* d_out, int out_size, void* d_ws, size_t ws_size,
                              hipStream_t stream)
{
    const float* imgf = (const float*)d_in[0];
    const float* txtf = (const float*)d_in[1];
    const int* ci     = (const int*)d_in[2];
    // d_in[3] = gt_indices (unused)
    const int* edges  = (const int*)d_in[4];
    const float* ars  = (const float*)d_in[5];
    const float* Wi   = (const float*)d_in[6];
    const float* bi   = (const float*)d_in[7];
    const float* Wt   = (const float*)d_in[8];
    const float* bt   = (const float*)d_in[9];
    const float* W0   = (const float*)d_in[10];
    const float* as0  = (const float*)d_in[11];
    const float* ad0  = (const float*)d_in[12];
    const float* b0   = (const float*)d_in[13];
    const float* W1   = (const float*)d_in[14];
    const float* as1  = (const float*)d_in[15];
    const float* ad1  = (const float*)d_in[16];
    const float* b1   = (const float*)d_in[17];
    const float* Wa   = (const float*)d_in[18];
    const float* ba   = (const float*)d_in[19];
    const float* Wd   = (const float*)d_in[20];
    const float* bd   = (const float*)d_in[21];
    (void)in_sizes; (void)n_in; (void)out_size; (void)ws_size;

    float* out0 = (float*)d_out;                  // N x 128 (gelu'd layer-2 output)
    float* pred = out0 + (size_t)N_NODES * HID;   // E x 2

    char* ws = (char*)d_ws;
    size_t off = 0;
    auto alloc = [&](size_t bytes) -> void* {
        void* p = ws + off;
        off += (bytes + 255) & ~(size_t)255;
        return p;
    };
    // node gets a zeroed 1 KiB tail: layer-0 GEMM over-reads up to 60 floats past
    // the last row (K padded 132->192); tail must be finite (0 * 0-weight = 0).
    float* node   = (float*)alloc((size_t)N_NODES * FEATP * 4 + 1024);
    float* hA     = (float*)alloc((size_t)N_NODES * HID * 4);
    float* as_buf = (float*)alloc((size_t)N_NODES * 4);
    float* ad_buf = (float*)alloc((size_t)N_NODES * 4);
    int* row_ptr  = (int*)alloc((size_t)(N_NODES + 1) * 4);
    int* cursor   = (int*)alloc((size_t)N_NODES * 4);
    int* csr_src  = (int*)alloc((size_t)N_EDGES * 4);
    float* adp    = (float*)alloc((size_t)N_NODES * 4 * 4);
    float* W0p    = (float*)alloc((size_t)KPAD0 * HID * 4);
    int* partials = (int*)alloc(512);

    const int gemm_mblocks = (N_NODES + 63) / 64;   // 1563 (4 waves x 16 rows / block)
    const int nwaveblocks = N_NODES / 4;            // 25000
    const int scan_blocks = (N_NODES + 1023) / 1024; // 98

    // CSR build
    hipMemsetAsync(cursor, 0, (size_t)N_NODES * 4, stream);
    hipMemsetAsync((char*)node + (size_t)N_NODES * FEATP * 4, 0, 1024, stream);
    hist_dst<<<(N_EDGES + 255) / 256, 256, 0, stream>>>(edges, cursor);
    scan_local<<<scan_blocks, 1024, 0, stream>>>(cursor, row_ptr, partials);
    scan_add<<<scan_blocks, 1024, 0, stream>>>(row_ptr, partials);
    copy_int<<<(N_NODES + 255) / 256, 256, 0, stream>>>(row_ptr, cursor, N_NODES);
    scatter_csr<<<(N_EDGES + 255) / 256, 256, 0, stream>>>(edges, cursor, csr_src);
    pad_W0<<<(KPAD0 * HID + 255) / 256, 256, 0, stream>>>(W0, W0p);

    // node features: gelu(concat(img@Wi+bi, txt@Wt+bt, ars)) scattered via content_indices
    gemm_rw<1><<<dim3(gemm_mblocks, 1), 256, 0, stream>>>(imgf, 512, N_NODES, 512, Wi, 64, bi, node, FEATP, 0, ci);
    gemm_rw<1><<<dim3(gemm_mblocks, 1), 256, 0, stream>>>(txtf, 768, N_NODES, 768, Wt, 64, bt, node, FEATP, 64, ci);
    ars_kernel<<<(N_NODES * 4 + 255) / 256, 256, 0, stream>>>(ars, ci, node);

    // GAT layer 0: h = node @ W0p (K padded to 192); aggregate; +b0; relu -> node (stride 128)
    gemm_rw<0><<<dim3(gemm_mblocks, 2), 256, 0, stream>>>(node, FEATP, N_NODES, KPAD0, W0p, HID, nullptr, hA, HID, 0, nullptr);
    attn_scores<<<nwaveblocks, 256, 0, stream>>>(hA, as0, ad0, as_buf, ad_buf);
    gat_aggregate<0><<<nwaveblocks, 256, 0, stream>>>(hA, as_buf, ad_buf, row_ptr, csr_src, b0, node);

    // GAT layer 1: h = x @ W1; aggregate; +b1; gelu -> d_out
    gemm_rw<0><<<dim3(gemm_mblocks, 2), 256, 0, stream>>>(node, HID, N_NODES, HID, W1, HID, nullptr, hA, HID, 0, nullptr);
    attn_scores<<<nwaveblocks, 256, 0, stream>>>(hA, as1, ad1, as_buf, ad_buf);
    gat_aggregate<1><<<nwaveblocks, 256, 0, stream>>>(hA, as_buf, ad_buf, row_ptr, csr_src, b1, out0);

    // heads + per-edge predictions
    head_proj<<<nwaveblocks, 256, 0, stream>>>(out0, Wa, ba, Wd, bd, adp);
    edge_pred<<<(N_EDGES + 255) / 256, 256, 0, stream>>>(edges, adp, pred);
}